// Round 1
// baseline (329.295 us; speedup 1.0000x reference)
//
#include <hip/hip_runtime.h>

// Elman RNN, SEQ=4096, BATCH=8192, HID=4, tanh, + fc(1) on last step.
// Design: 4 lanes per batch element (lane h owns hidden unit h).
//   - loop state is r = 1/(exp(2z)+1); h = 1-2r folded into weights so the
//     serial chain is: dpp -> fma tree -> exp2 -> add1 -> rcp.
//   - cross-lane h exchange via DPP quad_perm (never ds_bpermute).
//   - x prefetched 64 steps ahead in a register ring (compile-time indices).
constexpr int SEQ  = 4096;
constexpr int BATCH = 8192;
constexpr int U  = 8;   // steps per stage
constexpr int NB = 8;   // stages in ring -> 64-step prefetch lead

template <int CTRL>
__device__ __forceinline__ float qperm(float v) {
  int i = __builtin_bit_cast(int, v);
  i = __builtin_amdgcn_mov_dpp(i, CTRL, 0xF, 0xF, true);
  return __builtin_bit_cast(float, i);
}
// quad_perm ctrl: lane i reads lane sel[i] (within each group of 4)
// rot1 [1,2,3,0] = 0x39, rot2 [2,3,0,1] = 0x4E, rot3 [3,0,1,2] = 0x93

__global__ __launch_bounds__(256, 1) void rnn_kernel(
    const float* __restrict__ x, const float* __restrict__ h0,
    const float* __restrict__ W_ih, const float* __restrict__ b_ih,
    const float* __restrict__ W_hh, const float* __restrict__ b_hh,
    const float* __restrict__ fc_W, const float* __restrict__ fc_b,
    float* __restrict__ out) {
  const int tid = blockIdx.x * blockDim.x + threadIdx.x;
  const int b = tid >> 2;   // batch element
  const int h = tid & 3;    // hidden unit owned by this lane

  // Pre-scale weights: z = pre-activation; p = 2*log2(e)*z so exp2(p)=e^{2z}.
  // h_j = 1 - 2 r_j folded in:  p = A*x_t + Bc + sum_j W2[h][j] * r_j
  const float L2E2 = 2.0f * 1.4426950408889634f;  // 2*log2(e)
  const float w_self = W_hh[h * 4 + h];
  const float w_a = W_hh[h * 4 + ((h + 1) & 3)];
  const float w_b = W_hh[h * 4 + ((h + 2) & 3)];
  const float w_c = W_hh[h * 4 + ((h + 3) & 3)];
  const float A  = L2E2 * W_ih[h];
  const float Bc = L2E2 * (b_ih[h] + b_hh[h] + w_self + w_a + w_b + w_c);
  const float Ws = -2.0f * L2E2 * w_self;
  const float Wa = -2.0f * L2E2 * w_a;
  const float Wb = -2.0f * L2E2 * w_b;
  const float Wc = -2.0f * L2E2 * w_c;

  // r = (1 - h)/2 ; h0 is zeros in practice but honor it anyway.
  float r = fmaf(-0.5f, h0[b * 4 + h], 0.5f);

  const float* xp = x + b;  // x[t][b] at stride BATCH

  // Register-ring prefetch: NB stages of U steps, all indices compile-time.
  float buf[NB][U];
#pragma unroll
  for (int s = 0; s < NB; ++s)
#pragma unroll
    for (int i = 0; i < U; ++i)
      buf[s][i] = xp[(size_t)(s * U + i) * BATCH];

  for (int stage = 0; stage < SEQ / U; stage += NB) {
#pragma unroll
    for (int s = 0; s < NB; ++s) {
#pragma unroll
      for (int i = 0; i < U; ++i) {
        const float c  = fmaf(buf[s][i], A, Bc);  // off critical path
        const float ra = qperm<0x39>(r);          // r_{h+1}
        const float rb = qperm<0x4E>(r);          // r_{h+2}
        const float rc = qperm<0x93>(r);          // r_{h+3}
        float t1 = fmaf(Ws, r, c);
        t1 = fmaf(Wa, ra, t1);
        const float t2 = fmaf(Wb, rb, Wc * rc);
        const float p = t1 + t2;
        const float e = __builtin_amdgcn_exp2f(p);  // e^{2z}
        r = __builtin_amdgcn_rcpf(e + 1.0f);        // next state
      }
      // refill this ring slot with data NB stages ahead (uniform guard)
      const int base = (stage + s + NB) * U;
      if (base < SEQ) {
#pragma unroll
        for (int i = 0; i < U; ++i)
          buf[s][i] = xp[(size_t)(base + i) * BATCH];
      }
    }
  }

  const float hfin = fmaf(-2.0f, r, 1.0f);  // h = 1 - 2r
  // hn: (1, BATCH, 4) flat at offset BATCH
  out[BATCH + b * 4 + h] = hfin;
  // y_last[b] = sum_h hfin_h * fc_W[h] + fc_b  (quad butterfly via dpp)
  float tsum = hfin * fc_W[h];
  tsum += qperm<0x39>(tsum);  // t_h + t_{h+1}
  tsum += qperm<0x4E>(tsum);  // full quad sum in every lane
  if (h == 0) out[b] = tsum + fc_b[0];
}

extern "C" void kernel_launch(void* const* d_in, const int* in_sizes, int n_in,
                              void* d_out, int out_size, void* d_ws, size_t ws_size,
                              hipStream_t stream) {
  const float* x    = (const float*)d_in[0];
  const float* h0   = (const float*)d_in[1];
  const float* W_ih = (const float*)d_in[2];
  const float* b_ih = (const float*)d_in[3];
  const float* W_hh = (const float*)d_in[4];
  const float* b_hh = (const float*)d_in[5];
  const float* fc_W = (const float*)d_in[6];
  const float* fc_b = (const float*)d_in[7];
  float* out = (float*)d_out;

  const int threads = BATCH * 4;  // 4 lanes per batch element
  dim3 block(256);
  dim3 grid(threads / 256);  // 128 blocks
  rnn_kernel<<<grid, block, 0, stream>>>(x, h0, W_ih, b_ih, W_hh, b_hh, fc_W,
                                         fc_b, out);
}

// Round 2
// 323.404 us; speedup vs baseline: 1.0182x; 1.0182x over previous
//
#include <hip/hip_runtime.h>

// Elman RNN, SEQ=4096, BATCH=8192, HID=4, tanh, + fc(1) on last step.
// Latency-chain-bound: wall time = 4096 * per-step serial chain.
// Design: 4 lanes per batch element (lane h owns hidden unit h).
//   - loop state r = 1/(exp(2z)+1); h = 1-2r folded into pre-scaled weights.
//     Serial chain per step: (dpp hazard) dpp -> 3-fma tree -> exp2 -> +1 -> rcp.
//   - cross-lane h exchange via DPP quad_perm (operand network, no LDS).
//   - x prefetch: explicit 2x16-float double buffer (32 VGPRs), refill
//     interleaved per step, epilogue peeled. Round-1's 64-float ring was NOT
//     kept in registers (VGPR_Count=56 < ring size) -> scratch/late loads on
//     the critical chain. This version is sized to provably fit.
constexpr int SEQ   = 4096;
constexpr int BATCH = 8192;
constexpr int U     = 16;  // steps per buffer half

template <int CTRL>
__device__ __forceinline__ float qperm(float v) {
  int i = __builtin_bit_cast(int, v);
  i = __builtin_amdgcn_mov_dpp(i, CTRL, 0xF, 0xF, true);
  return __builtin_bit_cast(float, i);
}
// quad_perm ctrl: rot1 [1,2,3,0]=0x39, rot2 [2,3,0,1]=0x4E, rot3 [3,0,1,2]=0x93

__global__ __launch_bounds__(64, 1) void rnn_kernel(
    const float* __restrict__ x, const float* __restrict__ h0,
    const float* __restrict__ W_ih, const float* __restrict__ b_ih,
    const float* __restrict__ W_hh, const float* __restrict__ b_hh,
    const float* __restrict__ fc_W, const float* __restrict__ fc_b,
    float* __restrict__ out) {
  const int tid = blockIdx.x * 64 + threadIdx.x;
  const int b = tid >> 2;   // batch element
  const int h = tid & 3;    // hidden unit owned by this lane

  // p = 2*log2(e)*z so exp2(p) = e^{2z}; h_j = 1-2r_j folded into weights.
  const float L2E2 = 2.0f * 1.4426950408889634f;
  const float w_self = W_hh[h * 4 + h];
  const float w_a = W_hh[h * 4 + ((h + 1) & 3)];
  const float w_b = W_hh[h * 4 + ((h + 2) & 3)];
  const float w_c = W_hh[h * 4 + ((h + 3) & 3)];
  const float A  = L2E2 * W_ih[h];
  const float Bc = L2E2 * (b_ih[h] + b_hh[h] + w_self + w_a + w_b + w_c);
  const float Ws = -2.0f * L2E2 * w_self;
  const float Wa = -2.0f * L2E2 * w_a;
  const float Wb = -2.0f * L2E2 * w_b;
  const float Wc = -2.0f * L2E2 * w_c;

  float r = fmaf(-0.5f, h0[b * 4 + h], 0.5f);  // r = (1-h)/2

  const float* xp = x + b;  // x[t][b] at stride BATCH

  float bufA[U], bufB[U];
#pragma unroll
  for (int i = 0; i < U; ++i) bufA[i] = xp[(size_t)i * BATCH];
#pragma unroll
  for (int i = 0; i < U; ++i) bufB[i] = xp[(size_t)(U + i) * BATCH];

  auto step = [&](float xv) {
    // dpps issued right after r is produced: pay the VALU->DPP hazard once.
    const float ra = qperm<0x39>(r);
    const float rb = qperm<0x4E>(r);
    const float rc = qperm<0x93>(r);
    const float c  = fmaf(xv, A, Bc);          // off critical path
    float t1 = fmaf(Ws, r, c);                 // overlaps with dpp latency
    t1 = fmaf(Wa, ra, t1);
    const float t2 = fmaf(Wb, rb, Wc * rc);
    const float p = t1 + t2;
    const float e = __builtin_amdgcn_exp2f(p); // e^{2z}
    r = __builtin_amdgcn_rcpf(e + 1.0f);
  };

  // Main loop: 2U steps per iteration, per-step interleaved refill 2U ahead.
  for (int t0 = 0; t0 <= SEQ - 4 * U; t0 += 2 * U) {
#pragma unroll
    for (int i = 0; i < U; ++i) {
      step(bufA[i]);
      bufA[i] = xp[(size_t)(t0 + 2 * U + i) * BATCH];
    }
#pragma unroll
    for (int i = 0; i < U; ++i) {
      step(bufB[i]);
      bufB[i] = xp[(size_t)(t0 + 3 * U + i) * BATCH];
    }
  }
  // Epilogue: last 2U steps, no refill (buffers hold t = SEQ-2U .. SEQ-1).
#pragma unroll
  for (int i = 0; i < U; ++i) step(bufA[i]);
#pragma unroll
  for (int i = 0; i < U; ++i) step(bufB[i]);

  const float hfin = fmaf(-2.0f, r, 1.0f);  // h = 1 - 2r
  out[BATCH + b * 4 + h] = hfin;            // hn: (1,BATCH,4) at offset BATCH
  float tsum = hfin * fc_W[h];              // y = fc(h_last), quad reduction
  tsum += qperm<0x39>(tsum);
  tsum += qperm<0x4E>(tsum);
  if (h == 0) out[b] = tsum + fc_b[0];
}

extern "C" void kernel_launch(void* const* d_in, const int* in_sizes, int n_in,
                              void* d_out, int out_size, void* d_ws, size_t ws_size,
                              hipStream_t stream) {
  const float* x    = (const float*)d_in[0];
  const float* h0   = (const float*)d_in[1];
  const float* W_ih = (const float*)d_in[2];
  const float* b_ih = (const float*)d_in[3];
  const float* W_hh = (const float*)d_in[4];
  const float* b_hh = (const float*)d_in[5];
  const float* fc_W = (const float*)d_in[6];
  const float* fc_b = (const float*)d_in[7];
  float* out = (float*)d_out;

  // 4 lanes per batch element -> 32768 threads; 64-thread blocks spread
  // 512 single-wave blocks evenly across 256 CUs (latency-bound regime).
  dim3 block(64);
  dim3 grid(BATCH * 4 / 64);  // 512 blocks
  rnn_kernel<<<grid, block, 0, stream>>>(x, h0, W_ih, b_ih, W_hh, b_hh, fc_W,
                                         fc_b, out);
}